// Round 1
// baseline (1259.600 us; speedup 1.0000x reference)
//
#include <hip/hip_runtime.h>
#include <hip/hip_bf16.h>
#include <math.h>

#define Bc 8
#define Tc 8192
#define NTOK 256
#define Dc 512
#define TXT 768
#define TEc 2048
#define Hc 8
#define DHc 64

__device__ __forceinline__ float warp32_reduce_sum(float v) {
    v += __shfl_xor(v, 16);
    v += __shfl_xor(v, 8);
    v += __shfl_xor(v, 4);
    v += __shfl_xor(v, 2);
    v += __shfl_xor(v, 1);
    return v;
}

// ---------------------------------------------------------------------------
// Kernel 1: xt = LN(xf); k = softmax((xt@Wk+bk) per 64-head); v = xt@Wv+bv
// grid 256 blocks (8 rows each), 256 threads
// ---------------------------------------------------------------------------
__global__ void kv_kernel(const float* __restrict__ xf,
                          const float* __restrict__ ln_t_g, const float* __restrict__ ln_t_b,
                          const float* __restrict__ Wk, const float* __restrict__ bk,
                          const float* __restrict__ Wv, const float* __restrict__ bv,
                          float* __restrict__ kout, float* __restrict__ vout) {
    __shared__ float xs[8][TXT];
    const int tid = threadIdx.x;
    const int g = tid >> 5, lane = tid & 31;
    const int row0 = blockIdx.x * 8;

    {   // LN of row (row0+g), 32 lanes x 24 elems
        const int row = row0 + g;
        const float* src = xf + (size_t)row * TXT;
        float vals[24];
        float s = 0.f, ss = 0.f;
#pragma unroll
        for (int j = 0; j < 24; ++j) {
            float v = src[lane + 32 * j];
            vals[j] = v; s += v; ss += v * v;
        }
        s = warp32_reduce_sum(s); ss = warp32_reduce_sum(ss);
        float mean = s * (1.f / TXT);
        float var = ss * (1.f / TXT) - mean * mean;
        float rs = rsqrtf(var + 1e-5f);
#pragma unroll
        for (int j = 0; j < 24; ++j) {
            int c = lane + 32 * j;
            xs[g][c] = (vals[j] - mean) * rs * ln_t_g[c] + ln_t_b[c];
        }
    }
    __syncthreads();

    const int c0 = 2 * tid;
    float ka[8][2] = {{0.f}}, va[8][2] = {{0.f}};
    for (int kk = 0; kk < TXT; ++kk) {
        float2 wk = *(const float2*)&Wk[(size_t)kk * Dc + c0];
        float2 wv = *(const float2*)&Wv[(size_t)kk * Dc + c0];
#pragma unroll
        for (int r = 0; r < 8; ++r) {
            float a = xs[r][kk];
            ka[r][0] += a * wk.x; ka[r][1] += a * wk.y;
            va[r][0] += a * wv.x; va[r][1] += a * wv.y;
        }
    }
    float bk0 = bk[c0], bk1 = bk[c0 + 1], bv0 = bv[c0], bv1 = bv[c0 + 1];
    // softmax over 64-wide head segment (32 threads x 2 cols), for k only
#pragma unroll
    for (int r = 0; r < 8; ++r) {
        float k0 = ka[r][0] + bk0, k1 = ka[r][1] + bk1;
        float m = fmaxf(k0, k1);
        m = fmaxf(m, __shfl_xor(m, 16)); m = fmaxf(m, __shfl_xor(m, 8));
        m = fmaxf(m, __shfl_xor(m, 4));  m = fmaxf(m, __shfl_xor(m, 2));
        m = fmaxf(m, __shfl_xor(m, 1));
        float e0 = expf(k0 - m), e1 = expf(k1 - m);
        float ssum = warp32_reduce_sum(e0 + e1);
        float inv = 1.f / ssum;
        size_t o = (size_t)(row0 + r) * Dc + c0;
        kout[o] = e0 * inv; kout[o + 1] = e1 * inv;
        vout[o] = va[r][0] + bv0; vout[o + 1] = va[r][1] + bv1;
    }
}

// ---------------------------------------------------------------------------
// Kernel 2: attn[b,h,d,l] = sum_n k[b,n,h,d] * v[b,n,h,l]
// grid 64 blocks (b,h), 256 threads; thread owns (d = t>>2, 16 l's)
// ---------------------------------------------------------------------------
__global__ void attn_kernel(const float* __restrict__ kbuf, const float* __restrict__ vbuf,
                            float* __restrict__ attn) {
    __shared__ float ks[16][DHc], vs[16][DHc];
    const int tid = threadIdx.x;
    const int b = blockIdx.x >> 3, h = blockIdx.x & 7;
    const int d = tid >> 2, lb = (tid & 3) * 16;
    float acc[16] = {0.f};
    for (int nt = 0; nt < 16; ++nt) {
        __syncthreads();
#pragma unroll
        for (int j = 0; j < 4; ++j) {
            int idx = tid + 256 * j;
            int nn = idx >> 6, cc = idx & 63;
            size_t o = (size_t)(b * NTOK + nt * 16 + nn) * Dc + h * DHc + cc;
            ks[nn][cc] = kbuf[o];
            vs[nn][cc] = vbuf[o];
        }
        __syncthreads();
#pragma unroll
        for (int nn = 0; nn < 16; ++nn) {
            float kd = ks[nn][d];
#pragma unroll
            for (int i = 0; i < 16; ++i) acc[i] += kd * vs[nn][lb + i];
        }
    }
    size_t o = ((size_t)(b * 8 + h) * DHc + d) * DHc + lb;
#pragma unroll
    for (int i = 0; i < 16; ++i) attn[o + i] = acc[i];
}

// ---------------------------------------------------------------------------
// Kernel 3: eo[b, :] = silu(emb[b]) @ emb_W + emb_b   (eo is [B][2*D])
// grid 32 blocks = (b, col-chunk of 256), 256 threads
// ---------------------------------------------------------------------------
__global__ void emb_kernel(const float* __restrict__ emb, const float* __restrict__ emb_W,
                           const float* __restrict__ emb_b, float* __restrict__ eo) {
    __shared__ float s[TEc];
    const int tid = threadIdx.x;
    const int b = blockIdx.x >> 2, chunk = blockIdx.x & 3;
#pragma unroll
    for (int j = 0; j < 8; ++j) {
        int idx = tid + 256 * j;
        float e = emb[b * TEc + idx];
        s[idx] = e / (1.f + expf(-e));   // silu
    }
    __syncthreads();
    int col = chunk * 256 + tid;
    float acc = emb_b[col];
    for (int kk = 0; kk < TEc; ++kk)
        acc += s[kk] * emb_W[(size_t)kk * (2 * Dc) + col];
    eo[b * (2 * Dc) + col] = acc;
}

// ---------------------------------------------------------------------------
// Kernel 4: fused main pipeline over 16-row tiles.
// grid 4096 blocks, 128 threads; thread owns 16 rows x 4 cols.
// ---------------------------------------------------------------------------
__global__ void __launch_bounds__(128) main_kernel(
    const float* __restrict__ x,
    const float* __restrict__ ln_x_g, const float* __restrict__ ln_x_b,
    const float* __restrict__ Wq, const float* __restrict__ bq,
    const float* __restrict__ attn, const float* __restrict__ eo,
    const float* __restrict__ ln_o_g, const float* __restrict__ ln_o_b,
    const float* __restrict__ out_W, const float* __restrict__ out_b,
    float* __restrict__ out) {
    __shared__ float buf[16][Dc];
    const int tid = threadIdx.x;
    const int row0 = blockIdx.x * 16;
    const int b = row0 >> 13;             // row0 / T
    const int g = tid >> 5, lane = tid & 31;
    const int c0 = 4 * tid;               // 4 cols per thread
    const int h = tid >> 4;               // head of these cols

    // ---- Phase 1: LN(x rows) -> buf
#pragma unroll
    for (int rr = 0; rr < 4; ++rr) {
        int r = g * 4 + rr;
        const float* src = x + (size_t)(row0 + r) * Dc;
        float vals[16];
        float s = 0.f, ss = 0.f;
#pragma unroll
        for (int j = 0; j < 16; ++j) {
            float v = src[lane + 32 * j];
            vals[j] = v; s += v; ss += v * v;
        }
        s = warp32_reduce_sum(s); ss = warp32_reduce_sum(ss);
        float mean = s * (1.f / Dc), var = ss * (1.f / Dc) - mean * mean;
        float rs = rsqrtf(var + 1e-5f);
#pragma unroll
        for (int j = 0; j < 16; ++j) {
            int c = lane + 32 * j;
            buf[r][c] = (vals[j] - mean) * rs * ln_x_g[c] + ln_x_b[c];
        }
    }
    __syncthreads();

    float acc[16][4];
    // ---- Phase 2: q_pre = buf @ Wq + bq
    {
        float4 bq4 = *(const float4*)&bq[c0];
#pragma unroll
        for (int r = 0; r < 16; ++r) { acc[r][0] = bq4.x; acc[r][1] = bq4.y; acc[r][2] = bq4.z; acc[r][3] = bq4.w; }
        for (int kk = 0; kk < Dc; ++kk) {
            float4 w = *(const float4*)&Wq[(size_t)kk * Dc + c0];
#pragma unroll
            for (int r = 0; r < 16; ++r) {
                float a = buf[r][kk];
                acc[r][0] += a * w.x; acc[r][1] += a * w.y; acc[r][2] += a * w.z; acc[r][3] += a * w.w;
            }
        }
    }
    // ---- softmax per (row, head): 16-lane groups, 4 cols each
#pragma unroll
    for (int r = 0; r < 16; ++r) {
        float m = fmaxf(fmaxf(acc[r][0], acc[r][1]), fmaxf(acc[r][2], acc[r][3]));
        m = fmaxf(m, __shfl_xor(m, 8)); m = fmaxf(m, __shfl_xor(m, 4));
        m = fmaxf(m, __shfl_xor(m, 2)); m = fmaxf(m, __shfl_xor(m, 1));
        float e0 = expf(acc[r][0] - m), e1 = expf(acc[r][1] - m);
        float e2 = expf(acc[r][2] - m), e3 = expf(acc[r][3] - m);
        float ssum = e0 + e1 + e2 + e3;
        ssum += __shfl_xor(ssum, 8); ssum += __shfl_xor(ssum, 4);
        ssum += __shfl_xor(ssum, 2); ssum += __shfl_xor(ssum, 1);
        float inv = 1.f / ssum;
        acc[r][0] = e0 * inv; acc[r][1] = e1 * inv; acc[r][2] = e2 * inv; acc[r][3] = e3 * inv;
    }
    __syncthreads();           // all GEMM1 reads of buf complete
#pragma unroll
    for (int r = 0; r < 16; ++r) {
        float4 t4 = make_float4(acc[r][0], acc[r][1], acc[r][2], acc[r][3]);
        *(float4*)&buf[r][c0] = t4;
    }
    __syncthreads();

    // ---- Phase 3: out = q @ attn[b]   (per head 64x64)
    const float* ap = attn + (size_t)(b * 8 + h) * DHc * DHc + (c0 & 63);
#pragma unroll
    for (int r = 0; r < 16; ++r) { acc[r][0] = 0.f; acc[r][1] = 0.f; acc[r][2] = 0.f; acc[r][3] = 0.f; }
    for (int dd = 0; dd < DHc; ++dd) {
        float4 av = *(const float4*)&ap[dd * DHc];
#pragma unroll
        for (int r = 0; r < 16; ++r) {
            float qv = buf[r][h * DHc + dd];
            acc[r][0] += qv * av.x; acc[r][1] += qv * av.y; acc[r][2] += qv * av.z; acc[r][3] += qv * av.w;
        }
    }
    __syncthreads();
#pragma unroll
    for (int r = 0; r < 16; ++r) {
        float4 t4 = make_float4(acc[r][0], acc[r][1], acc[r][2], acc[r][3]);
        *(float4*)&buf[r][c0] = t4;
    }
    __syncthreads();

    // ---- Phase 4: LN(out)*(1+scale)+shift, then SiLU -> buf
    const float* scale = eo + b * (2 * Dc);
    const float* shift = scale + Dc;
#pragma unroll
    for (int rr = 0; rr < 4; ++rr) {
        int r = g * 4 + rr;
        float vals[16];
        float s = 0.f, ss = 0.f;
#pragma unroll
        for (int j = 0; j < 16; ++j) {
            float v = buf[r][lane + 32 * j];
            vals[j] = v; s += v; ss += v * v;
        }
        s = warp32_reduce_sum(s); ss = warp32_reduce_sum(ss);
        float mean = s * (1.f / Dc), var = ss * (1.f / Dc) - mean * mean;
        float rs = rsqrtf(var + 1e-5f);
#pragma unroll
        for (int j = 0; j < 16; ++j) {
            int c = lane + 32 * j;
            float v = (vals[j] - mean) * rs * ln_o_g[c] + ln_o_b[c];
            v = v * (1.f + scale[c]) + shift[c];
            buf[r][c] = v / (1.f + expf(-v));   // silu
        }
    }
    __syncthreads();

    // ---- Phase 5: GEMM2 (out_W) + out_b + residual x
    {
        float4 ob4 = *(const float4*)&out_b[c0];
#pragma unroll
        for (int r = 0; r < 16; ++r) { acc[r][0] = ob4.x; acc[r][1] = ob4.y; acc[r][2] = ob4.z; acc[r][3] = ob4.w; }
        for (int kk = 0; kk < Dc; ++kk) {
            float4 w = *(const float4*)&out_W[(size_t)kk * Dc + c0];
#pragma unroll
            for (int r = 0; r < 16; ++r) {
                float a = buf[r][kk];
                acc[r][0] += a * w.x; acc[r][1] += a * w.y; acc[r][2] += a * w.z; acc[r][3] += a * w.w;
            }
        }
#pragma unroll
        for (int r = 0; r < 16; ++r) {
            float4 xv = *(const float4*)&x[(size_t)(row0 + r) * Dc + c0];
            float4 o4 = make_float4(acc[r][0] + xv.x, acc[r][1] + xv.y,
                                    acc[r][2] + xv.z, acc[r][3] + xv.w);
            *(float4*)&out[(size_t)(row0 + r) * Dc + c0] = o4;
        }
    }
}

// ---------------------------------------------------------------------------
extern "C" void kernel_launch(void* const* d_in, const int* in_sizes, int n_in,
                              void* d_out, int out_size, void* d_ws, size_t ws_size,
                              hipStream_t stream) {
    const float* x      = (const float*)d_in[0];
    const float* xf     = (const float*)d_in[1];
    const float* emb    = (const float*)d_in[2];
    const float* ln_t_g = (const float*)d_in[5];
    const float* ln_t_b = (const float*)d_in[6];
    const float* Wq     = (const float*)d_in[7];
    const float* bq     = (const float*)d_in[8];
    const float* Wk     = (const float*)d_in[9];
    const float* bk     = (const float*)d_in[10];
    const float* Wv     = (const float*)d_in[11];
    const float* bv     = (const float*)d_in[12];
    const float* emb_W  = (const float*)d_in[13];
    const float* emb_b  = (const float*)d_in[14];
    const float* ln_x_g = (const float*)d_in[3];
    const float* ln_x_b = (const float*)d_in[4];
    const float* ln_o_g = (const float*)d_in[15];
    const float* ln_o_b = (const float*)d_in[16];
    const float* out_W  = (const float*)d_in[17];
    const float* out_b  = (const float*)d_in[18];
    float* out = (float*)d_out;

    float* ws   = (float*)d_ws;
    float* kbuf = ws;                                   // 2048*512
    float* vbuf = kbuf + (size_t)2048 * 512;            // 2048*512
    float* attn = vbuf + (size_t)2048 * 512;            // 8*8*64*64
    float* eo   = attn + (size_t)8 * 8 * 64 * 64;       // 8*1024

    hipLaunchKernelGGL(kv_kernel, dim3(NTOK * Bc / 8), dim3(256), 0, stream,
                       xf, ln_t_g, ln_t_b, Wk, bk, Wv, bv, kbuf, vbuf);
    hipLaunchKernelGGL(attn_kernel, dim3(Bc * Hc), dim3(256), 0, stream,
                       kbuf, vbuf, attn);
    hipLaunchKernelGGL(emb_kernel, dim3(Bc * 4), dim3(256), 0, stream,
                       emb, emb_W, emb_b, eo);
    hipLaunchKernelGGL(main_kernel, dim3(Bc * Tc / 16), dim3(128), 0, stream,
                       x, ln_x_g, ln_x_b, Wq, bq, attn, eo,
                       ln_o_g, ln_o_b, out_W, out_b, out);
}

// Round 2
// 464.334 us; speedup vs baseline: 2.7127x; 2.7127x over previous
//
#include <hip/hip_runtime.h>
#include <hip/hip_bf16.h>
#include <math.h>

#define Bc 8
#define Tc 8192
#define NTOK 256
#define Dc 512
#define TXT 768
#define TEc 2048
#define Hc 8
#define DHc 64
#define MROWS (Bc * Tc)   // 65536

typedef __attribute__((ext_vector_type(8))) short bf16x8v;
typedef __attribute__((ext_vector_type(8))) unsigned short u16x8;
typedef __attribute__((ext_vector_type(4))) float f32x4;

#define MFMA16(a, b, c) __builtin_amdgcn_mfma_f32_16x16x32_bf16(a, b, c, 0, 0, 0)

__device__ __forceinline__ unsigned short f2bf(float f) {
    __hip_bfloat16 h = __float2bfloat16(f);
    return __builtin_bit_cast(unsigned short, h);
}
__device__ __forceinline__ float bf2f(unsigned short u) {
    unsigned int x = ((unsigned int)u) << 16;
    return __builtin_bit_cast(float, x);
}

typedef __attribute__((address_space(3))) unsigned int lds_u32_t;
typedef __attribute__((address_space(1))) const unsigned int gbl_u32_t;
__device__ __forceinline__ void gload16(const unsigned short* g, short* l) {
    __builtin_amdgcn_global_load_lds((gbl_u32_t*)g, (lds_u32_t*)l, 16, 0, 0);
}

__device__ __forceinline__ float warp32_reduce_sum(float v) {
    v += __shfl_xor(v, 16); v += __shfl_xor(v, 8); v += __shfl_xor(v, 4);
    v += __shfl_xor(v, 2);  v += __shfl_xor(v, 1);
    return v;
}

// ---------------------------------------------------------------------------
// wprep: Wq[512][512] f32 -> Wq_t[n][k] bf16 ; same for out_W
// ---------------------------------------------------------------------------
__global__ void wprep_kernel(const float* __restrict__ Wq, const float* __restrict__ oW,
                             unsigned short* __restrict__ Wqt, unsigned short* __restrict__ oWt) {
    int n = blockIdx.x;
    const float* W = blockIdx.y ? oW : Wq;
    unsigned short* Wt = blockIdx.y ? oWt : Wqt;
    for (int k = threadIdx.x; k < Dc; k += 256)
        Wt[(size_t)n * Dc + k] = f2bf(W[(size_t)k * Dc + n]);
}

// ---------------------------------------------------------------------------
// K0: A1 = LN(x) in bf16.  one wave per row.
// ---------------------------------------------------------------------------
__global__ void __launch_bounds__(256) ln_x_kernel(const float* __restrict__ x,
                                                   const float* __restrict__ g,
                                                   const float* __restrict__ bt,
                                                   unsigned short* __restrict__ A1) {
    int w = threadIdx.x >> 6, l = threadIdx.x & 63;
    int row = blockIdx.x * 4 + w;
    const float* src = x + (size_t)row * Dc;
    float4 a0 = *(const float4*)&src[l * 8];
    float4 a1 = *(const float4*)&src[l * 8 + 4];
    float vals[8] = {a0.x, a0.y, a0.z, a0.w, a1.x, a1.y, a1.z, a1.w};
    float s = 0.f, ss = 0.f;
#pragma unroll
    for (int j = 0; j < 8; ++j) { s += vals[j]; ss += vals[j] * vals[j]; }
#pragma unroll
    for (int m = 1; m <= 32; m <<= 1) { s += __shfl_xor(s, m); ss += __shfl_xor(ss, m); }
    float mean = s * (1.f / Dc), var = ss * (1.f / Dc) - mean * mean;
    float rs = rsqrtf(var + 1e-5f);
    u16x8 o;
#pragma unroll
    for (int j = 0; j < 8; ++j) {
        int c = l * 8 + j;
        o[j] = f2bf((vals[j] - mean) * rs * g[c] + bt[c]);
    }
    *(u16x8*)&A1[(size_t)row * Dc + l * 8] = o;
}

// ---------------------------------------------------------------------------
// kv_kernel: unchanged from round 1 (fp32 k/v)
// ---------------------------------------------------------------------------
__global__ void kv_kernel(const float* __restrict__ xf,
                          const float* __restrict__ ln_t_g, const float* __restrict__ ln_t_b,
                          const float* __restrict__ Wk, const float* __restrict__ bk,
                          const float* __restrict__ Wv, const float* __restrict__ bv,
                          float* __restrict__ kout, float* __restrict__ vout) {
    __shared__ float xs[8][TXT];
    const int tid = threadIdx.x;
    const int g = tid >> 5, lane = tid & 31;
    const int row0 = blockIdx.x * 8;
    {
        const int row = row0 + g;
        const float* src = xf + (size_t)row * TXT;
        float vals[24];
        float s = 0.f, ss = 0.f;
#pragma unroll
        for (int j = 0; j < 24; ++j) {
            float v = src[lane + 32 * j];
            vals[j] = v; s += v; ss += v * v;
        }
        s = warp32_reduce_sum(s); ss = warp32_reduce_sum(ss);
        float mean = s * (1.f / TXT);
        float var = ss * (1.f / TXT) - mean * mean;
        float rs = rsqrtf(var + 1e-5f);
#pragma unroll
        for (int j = 0; j < 24; ++j) {
            int c = lane + 32 * j;
            xs[g][c] = (vals[j] - mean) * rs * ln_t_g[c] + ln_t_b[c];
        }
    }
    __syncthreads();
    const int c0 = 2 * tid;
    float ka[8][2] = {{0.f}}, va[8][2] = {{0.f}};
    for (int kk = 0; kk < TXT; ++kk) {
        float2 wk = *(const float2*)&Wk[(size_t)kk * Dc + c0];
        float2 wv = *(const float2*)&Wv[(size_t)kk * Dc + c0];
#pragma unroll
        for (int r = 0; r < 8; ++r) {
            float a = xs[r][kk];
            ka[r][0] += a * wk.x; ka[r][1] += a * wk.y;
            va[r][0] += a * wv.x; va[r][1] += a * wv.y;
        }
    }
    float bk0 = bk[c0], bk1 = bk[c0 + 1], bv0 = bv[c0], bv1 = bv[c0 + 1];
#pragma unroll
    for (int r = 0; r < 8; ++r) {
        float k0 = ka[r][0] + bk0, k1 = ka[r][1] + bk1;
        float m = fmaxf(k0, k1);
        m = fmaxf(m, __shfl_xor(m, 16)); m = fmaxf(m, __shfl_xor(m, 8));
        m = fmaxf(m, __shfl_xor(m, 4));  m = fmaxf(m, __shfl_xor(m, 2));
        m = fmaxf(m, __shfl_xor(m, 1));
        float e0 = expf(k0 - m), e1 = expf(k1 - m);
        float ssum = warp32_reduce_sum(e0 + e1);
        float inv = 1.f / ssum;
        size_t o = (size_t)(row0 + r) * Dc + c0;
        kout[o] = e0 * inv; kout[o + 1] = e1 * inv;
        vout[o] = va[r][0] + bv0; vout[o + 1] = va[r][1] + bv1;
    }
}

// ---------------------------------------------------------------------------
// attn_kernel: attn_t[b,h][l][d] = sum_n k[b,n,h,d]*v[b,n,h,l]  (bf16, transposed)
// ---------------------------------------------------------------------------
__global__ void attn_kernel(const float* __restrict__ kbuf, const float* __restrict__ vbuf,
                            unsigned short* __restrict__ attn_t) {
    __shared__ float ks[16][DHc], vs[16][DHc];
    const int tid = threadIdx.x;
    const int b = blockIdx.x >> 3, h = blockIdx.x & 7;
    const int d = tid >> 2, lb = (tid & 3) * 16;
    float acc[16] = {0.f};
    for (int nt = 0; nt < 16; ++nt) {
        __syncthreads();
#pragma unroll
        for (int j = 0; j < 4; ++j) {
            int idx = tid + 256 * j;
            int nn = idx >> 6, cc = idx & 63;
            size_t o = (size_t)(b * NTOK + nt * 16 + nn) * Dc + h * DHc + cc;
            ks[nn][cc] = kbuf[o];
            vs[nn][cc] = vbuf[o];
        }
        __syncthreads();
#pragma unroll
        for (int nn = 0; nn < 16; ++nn) {
            float kd = ks[nn][d];
#pragma unroll
            for (int i = 0; i < 16; ++i) acc[i] += kd * vs[nn][lb + i];
        }
    }
    // transposed bf16 store: attn_t[(b*8+h)*64 + l][d]
    size_t base = (size_t)(b * 8 + h) * DHc * DHc;
#pragma unroll
    for (int i = 0; i < 16; ++i)
        attn_t[base + (size_t)(lb + i) * DHc + d] = f2bf(acc[i]);
}

// ---------------------------------------------------------------------------
// emb_kernel: eo[b,:] = silu(emb[b]) @ emb_W + emb_b
// ---------------------------------------------------------------------------
__global__ void emb_kernel(const float* __restrict__ emb, const float* __restrict__ emb_W,
                           const float* __restrict__ emb_b, float* __restrict__ eo) {
    __shared__ float s[TEc];
    const int tid = threadIdx.x;
    const int b = blockIdx.x >> 2, chunk = blockIdx.x & 3;
#pragma unroll
    for (int j = 0; j < 8; ++j) {
        int idx = tid + 256 * j;
        float e = emb[b * TEc + idx];
        s[idx] = e / (1.f + expf(-e));
    }
    __syncthreads();
    int col = chunk * 256 + tid;
    float acc = emb_b[col];
    for (int kk = 0; kk < TEc; ++kk)
        acc += s[kk] * emb_W[(size_t)kk * (2 * Dc) + col];
    eo[b * (2 * Dc) + col] = acc;
}

// ---------------------------------------------------------------------------
// KA: GEMM1 (A1 @ Wq_t) + bq + per-head softmax + (q @ attn) -> out1 bf16
// 128x128 tile, BK=64, 4 waves (2x2), 16x16x32 MFMA
// ---------------------------------------------------------------------------
__global__ void __launch_bounds__(256) gemm1_kernel(
    const unsigned short* __restrict__ A1, const unsigned short* __restrict__ Wt,
    const float* __restrict__ bq, const unsigned short* __restrict__ attn_t,
    unsigned short* __restrict__ out1) {
    __shared__ short lds_s[16384];            // 32 KB: A [0:8192), B [8192:16384)
    short* Alds = lds_s;
    short* Blds = lds_s + 8192;

    const int tid = threadIdx.x, l = tid & 63, w = tid >> 6;
    const int lr = l & 15, lg = l >> 4;
    int raw = blockIdx.x;
    int swz = (raw & 7) * 256 + (raw >> 3);   // bijective XCD swizzle (2048 % 8 == 0)
    int mt = swz >> 2, nt = swz & 3;
    int row0 = mt * 128, col0 = nt * 128;
    int b = row0 >> 13;
    int wrow = (w >> 1) * 64, wcol = (w & 1) * 64;

    f32x4 acc[4][4] = {};
    const int cbase = w * 64 + l;

    for (int ks = 0; ks < 8; ++ks) {
#pragma unroll
        for (int i = 0; i < 4; ++i) {
            int c = i * 256 + cbase;
            int r = c >> 3, kc = c & 7;
            int koff = ks * 64 + ((kc ^ (r & 7)) << 3);   // pre-swizzled source
            gload16(A1 + (size_t)(row0 + r) * Dc + koff, &Alds[((i * 4 + w) * 64) * 8]);
            gload16(Wt + (size_t)(col0 + r) * Dc + koff, &Blds[((i * 4 + w) * 64) * 8]);
        }
        __syncthreads();
#pragma unroll
        for (int kk = 0; kk < 2; ++kk) {
            int kcw = kk * 4 + lg;
            bf16x8v af[4], bfr[4];
#pragma unroll
            for (int i = 0; i < 4; ++i) {
                int r = wrow + i * 16 + lr;
                af[i] = *(bf16x8v*)&Alds[(r * 8 + (kcw ^ (r & 7))) * 8];
            }
#pragma unroll
            for (int j = 0; j < 4; ++j) {
                int n = wcol + j * 16 + lr;
                bfr[j] = *(bf16x8v*)&Blds[(n * 8 + (kcw ^ (n & 7))) * 8];
            }
#pragma unroll
            for (int i = 0; i < 4; ++i)
#pragma unroll
                for (int j = 0; j < 4; ++j)
                    acc[i][j] = MFMA16(af[i], bfr[j], acc[i][j]);
        }
        __syncthreads();
    }

    // bias + per-(row,head) softmax: wave's 64 cols == one head
    float bqv[4];
#pragma unroll
    for (int j = 0; j < 4; ++j) bqv[j] = bq[col0 + wcol + j * 16 + lr];
#pragma unroll
    for (int i = 0; i < 4; ++i)
#pragma unroll
        for (int reg = 0; reg < 4; ++reg) {
            float v0 = acc[i][0][reg] + bqv[0], v1 = acc[i][1][reg] + bqv[1];
            float v2 = acc[i][2][reg] + bqv[2], v3 = acc[i][3][reg] + bqv[3];
            float m = fmaxf(fmaxf(v0, v1), fmaxf(v2, v3));
            m = fmaxf(m, __shfl_xor(m, 1)); m = fmaxf(m, __shfl_xor(m, 2));
            m = fmaxf(m, __shfl_xor(m, 4)); m = fmaxf(m, __shfl_xor(m, 8));
            float e0 = __expf(v0 - m), e1 = __expf(v1 - m);
            float e2 = __expf(v2 - m), e3 = __expf(v3 - m);
            float ssum = e0 + e1 + e2 + e3;
            ssum += __shfl_xor(ssum, 1); ssum += __shfl_xor(ssum, 2);
            ssum += __shfl_xor(ssum, 4); ssum += __shfl_xor(ssum, 8);
            float inv = 1.f / ssum;
            acc[i][0][reg] = e0 * inv; acc[i][1][reg] = e1 * inv;
            acc[i][2][reg] = e2 * inv; acc[i][3][reg] = e3 * inv;
        }

    // q -> swizzled LDS [128][128] bf16 (reuse staging buffers)
    short* qlds = lds_s;
#pragma unroll
    for (int i = 0; i < 4; ++i)
#pragma unroll
        for (int j = 0; j < 4; ++j)
#pragma unroll
            for (int reg = 0; reg < 4; ++reg) {
                int r = wrow + i * 16 + 4 * lg + reg;
                int c = wcol + j * 16 + lr;
                qlds[(r * 16 + ((c >> 3) ^ (r & 7))) * 8 + (c & 7)] = (short)f2bf(acc[i][j][reg]);
            }
    __syncthreads();

    // phase 3: out = q @ attn[b, head]   (64x64 per head, head == wave col range)
    int hw = nt * 2 + (wcol >> 6);
    const unsigned short* at = attn_t + (size_t)(b * 8 + hw) * DHc * DHc;
    bf16x8v bf2[4][2];
#pragma unroll
    for (int j = 0; j < 4; ++j)
#pragma unroll
        for (int kk = 0; kk < 2; ++kk)
            bf2[j][kk] = *(const bf16x8v*)&at[(j * 16 + lr) * DHc + kk * 32 + lg * 8];

    f32x4 acc2[4][4] = {};
#pragma unroll
    for (int kk = 0; kk < 2; ++kk) {
        int kcw = (wcol >> 3) + kk * 4 + lg;
#pragma unroll
        for (int i = 0; i < 4; ++i) {
            int r = wrow + i * 16 + lr;
            bf16x8v a = *(bf16x8v*)&qlds[(r * 16 + (kcw ^ (r & 7))) * 8];
#pragma unroll
            for (int j = 0; j < 4; ++j)
                acc2[i][j] = MFMA16(a, bf2[j][kk], acc2[i][j]);
        }
    }

    // store out1 bf16
#pragma unroll
    for (int i = 0; i < 4; ++i)
#pragma unroll
        for (int j = 0; j < 4; ++j)
#pragma unroll
            for (int reg = 0; reg < 4; ++reg) {
                int r = row0 + wrow + i * 16 + 4 * lg + reg;
                int c = col0 + wcol + j * 16 + lr;
                out1[(size_t)r * Dc + c] = f2bf(acc2[i][j][reg]);
            }
}

// ---------------------------------------------------------------------------
// Kmid: A2 = bf16( silu( LN(out1)*(1+scale)+shift ) )
// ---------------------------------------------------------------------------
__global__ void __launch_bounds__(256) mid_kernel(const unsigned short* __restrict__ out1,
                                                  const float* __restrict__ eo,
                                                  const float* __restrict__ g,
                                                  const float* __restrict__ bt,
                                                  unsigned short* __restrict__ A2) {
    int w = threadIdx.x >> 6, l = threadIdx.x & 63;
    int row = blockIdx.x * 4 + w;
    int b = row >> 13;
    u16x8 iv = *(const u16x8*)&out1[(size_t)row * Dc + l * 8];
    float vals[8];
    float s = 0.f, ss = 0.f;
#pragma unroll
    for (int j = 0; j < 8; ++j) {
        vals[j] = bf2f(iv[j]);
        s += vals[j]; ss += vals[j] * vals[j];
    }
#pragma unroll
    for (int m = 1; m <= 32; m <<= 1) { s += __shfl_xor(s, m); ss += __shfl_xor(ss, m); }
    float mean = s * (1.f / Dc), var = ss * (1.f / Dc) - mean * mean;
    float rs = rsqrtf(var + 1e-5f);
    const float* scl = eo + (size_t)b * (2 * Dc);
    const float* shf = scl + Dc;
    u16x8 o;
#pragma unroll
    for (int j = 0; j < 8; ++j) {
        int c = l * 8 + j;
        float t = (vals[j] - mean) * rs * g[c] + bt[c];
        t = t * (1.f + scl[c]) + shf[c];
        t = t / (1.f + __expf(-t));
        o[j] = f2bf(t);
    }
    *(u16x8*)&A2[(size_t)row * Dc + l * 8] = o;
}

// ---------------------------------------------------------------------------
// KB: out = x + (A2 @ oW_t) + out_b    (fp32 output)
// ---------------------------------------------------------------------------
__global__ void __launch_bounds__(256) gemm2_kernel(
    const unsigned short* __restrict__ A2, const unsigned short* __restrict__ Wt,
    const float* __restrict__ ob, const float* __restrict__ x,
    float* __restrict__ out) {
    __shared__ short lds_s[16384];
    short* Alds = lds_s;
    short* Blds = lds_s + 8192;

    const int tid = threadIdx.x, l = tid & 63, w = tid >> 6;
    const int lr = l & 15, lg = l >> 4;
    int raw = blockIdx.x;
    int swz = (raw & 7) * 256 + (raw >> 3);
    int mt = swz >> 2, nt = swz & 3;
    int row0 = mt * 128, col0 = nt * 128;
    int wrow = (w >> 1) * 64, wcol = (w & 1) * 64;

    f32x4 acc[4][4] = {};
    const int cbase = w * 64 + l;

    for (int ks = 0; ks < 8; ++ks) {
#pragma unroll
        for (int i = 0; i < 4; ++i) {
            int c = i * 256 + cbase;
            int r = c >> 3, kc = c & 7;
            int koff = ks * 64 + ((kc ^ (r & 7)) << 3);
            gload16(A2 + (size_t)(row0 + r) * Dc + koff, &Alds[((i * 4 + w) * 64) * 8]);
            gload16(Wt + (size_t)(col0 + r) * Dc + koff, &Blds[((i * 4 + w) * 64) * 8]);
        }
        __syncthreads();
#pragma unroll
        for (int kk = 0; kk < 2; ++kk) {
            int kcw = kk * 4 + lg;
            bf16x8v af[4], bfr[4];
#pragma unroll
            for (int i = 0; i < 4; ++i) {
                int r = wrow + i * 16 + lr;
                af[i] = *(bf16x8v*)&Alds[(r * 8 + (kcw ^ (r & 7))) * 8];
            }
#pragma unroll
            for (int j = 0; j < 4; ++j) {
                int n = wcol + j * 16 + lr;
                bfr[j] = *(bf16x8v*)&Blds[(n * 8 + (kcw ^ (n & 7))) * 8];
            }
#pragma unroll
            for (int i = 0; i < 4; ++i)
#pragma unroll
                for (int j = 0; j < 4; ++j)
                    acc[i][j] = MFMA16(af[i], bfr[j], acc[i][j]);
        }
        __syncthreads();
    }

    float obv[4];
#pragma unroll
    for (int j = 0; j < 4; ++j) obv[j] = ob[col0 + wcol + j * 16 + lr];
#pragma unroll
    for (int i = 0; i < 4; ++i)
#pragma unroll
        for (int j = 0; j < 4; ++j)
#pragma unroll
            for (int reg = 0; reg < 4; ++reg) {
                int r = row0 + wrow + i * 16 + 4 * lg + reg;
                int c = col0 + wcol + j * 16 + lr;
                size_t o = (size_t)r * Dc + c;
                out[o] = acc[i][j][reg] + obv[j] + x[o];
            }
}

// ---------------------------------------------------------------------------
extern "C" void kernel_launch(void* const* d_in, const int* in_sizes, int n_in,
                              void* d_out, int out_size, void* d_ws, size_t ws_size,
                              hipStream_t stream) {
    const float* x      = (const float*)d_in[0];
    const float* xf     = (const float*)d_in[1];
    const float* emb    = (const float*)d_in[2];
    const float* ln_x_g = (const float*)d_in[3];
    const float* ln_x_b = (const float*)d_in[4];
    const float* ln_t_g = (const float*)d_in[5];
    const float* ln_t_b = (const float*)d_in[6];
    const float* Wq     = (const float*)d_in[7];
    const float* bq     = (const float*)d_in[8];
    const float* Wk     = (const float*)d_in[9];
    const float* bk     = (const float*)d_in[10];
    const float* Wv     = (const float*)d_in[11];
    const float* bv     = (const float*)d_in[12];
    const float* emb_W  = (const float*)d_in[13];
    const float* emb_b  = (const float*)d_in[14];
    const float* ln_o_g = (const float*)d_in[15];
    const float* ln_o_b = (const float*)d_in[16];
    const float* out_W  = (const float*)d_in[17];
    const float* out_b  = (const float*)d_in[18];
    float* out = (float*)d_out;

    // ws layout
    float* ws = (float*)d_ws;
    float* kbuf = ws;                                   // 2048*512 f32
    float* vbuf = kbuf + (size_t)2048 * 512;            // 2048*512 f32
    float* eo   = vbuf + (size_t)2048 * 512;            // 8*1024 f32
    unsigned short* attn_t = (unsigned short*)(eo + 8 * 1024);   // 8*8*64*64 bf16
    unsigned short* Wqt = attn_t + (size_t)64 * 64 * 64;         // 512*512 bf16
    unsigned short* oWt = Wqt + (size_t)512 * 512;               // 512*512 bf16
    unsigned short* A1  = oWt + (size_t)512 * 512;               // 65536*512 bf16 (67MB)
    unsigned short* A2  = A1;                                    // overlay (A1 dead after KA)
    // out1 lives in the first half of d_out (bf16, 67MB of 134MB)
    unsigned short* out1 = (unsigned short*)d_out;

    hipLaunchKernelGGL(wprep_kernel, dim3(512, 2), dim3(256), 0, stream, Wq, out_W, Wqt, oWt);
    hipLaunchKernelGGL(ln_x_kernel, dim3(MROWS / 4), dim3(256), 0, stream, x, ln_x_g, ln_x_b, A1);
    hipLaunchKernelGGL(kv_kernel, dim3(NTOK * Bc / 8), dim3(256), 0, stream,
                       xf, ln_t_g, ln_t_b, Wk, bk, Wv, bv, kbuf, vbuf);
    hipLaunchKernelGGL(attn_kernel, dim3(Bc * Hc), dim3(256), 0, stream, kbuf, vbuf, attn_t);
    hipLaunchKernelGGL(emb_kernel, dim3(Bc * 4), dim3(256), 0, stream, emb, emb_W, emb_b, eo);
    hipLaunchKernelGGL(gemm1_kernel, dim3(MROWS / 128 * 4), dim3(256), 0, stream,
                       A1, Wqt, bq, attn_t, out1);
    hipLaunchKernelGGL(mid_kernel, dim3(MROWS / 4), dim3(256), 0, stream,
                       out1, eo, ln_o_g, ln_o_b, A2);
    hipLaunchKernelGGL(gemm2_kernel, dim3(MROWS / 128 * 4), dim3(256), 0, stream,
                       A2, oWt, out_b, x, out);
}

// Round 3
// 314.616 us; speedup vs baseline: 4.0036x; 1.4759x over previous
//
#include <hip/hip_runtime.h>
#include <hip/hip_bf16.h>
#include <math.h>

#define Bc 8
#define Tc 8192
#define NTOK 256
#define Dc 512
#define TXT 768
#define TEc 2048
#define Hc 8
#define DHc 64
#define MROWS (Bc * Tc)   // 65536

typedef __attribute__((ext_vector_type(8))) short bf16x8v;
typedef __attribute__((ext_vector_type(8))) unsigned short u16x8;
typedef __attribute__((ext_vector_type(4))) unsigned short u16x4;
typedef __attribute__((ext_vector_type(4))) float f32x4;

#define MFMA16(a, b, c) __builtin_amdgcn_mfma_f32_16x16x32_bf16(a, b, c, 0, 0, 0)

__device__ __forceinline__ unsigned short f2bf(float f) {
    __hip_bfloat16 h = __float2bfloat16(f);
    return __builtin_bit_cast(unsigned short, h);
}
__device__ __forceinline__ float bf2f(unsigned short u) {
    unsigned int x = ((unsigned int)u) << 16;
    return __builtin_bit_cast(float, x);
}

typedef __attribute__((address_space(3))) unsigned int lds_u32_t;
typedef __attribute__((address_space(1))) const unsigned int gbl_u32_t;
__device__ __forceinline__ void gload16(const unsigned short* g, short* l) {
    __builtin_amdgcn_global_load_lds((gbl_u32_t*)g, (lds_u32_t*)l, 16, 0, 0);
}

// ---------------------------------------------------------------------------
// transpose: dst[n][k] = bf16(src[k][n]); src K x N f32; dst row-stride rs
// ---------------------------------------------------------------------------
__global__ void __launch_bounds__(256) transpose_kernel(const float* __restrict__ src,
                                                        unsigned short* __restrict__ dst,
                                                        int N, int rs) {
    __shared__ float tile[64][65];
    int k0 = blockIdx.x * 64, n0 = blockIdx.y * 64;
    int tx = threadIdx.x & 63, tq = threadIdx.x >> 6;
#pragma unroll
    for (int i = 0; i < 16; ++i) {
        int kk = tq + i * 4;
        tile[kk][tx] = src[(size_t)(k0 + kk) * N + n0 + tx];
    }
    __syncthreads();
#pragma unroll
    for (int i = 0; i < 16; ++i) {
        int nn = tq + i * 4;
        dst[(size_t)(n0 + nn) * rs + k0 + tx] = f2bf(tile[tx][nn]);
    }
}

// ---------------------------------------------------------------------------
// ln_t: xt = bf16(LN(xf))  [2048][768], one wave per row
// ---------------------------------------------------------------------------
__global__ void __launch_bounds__(256) ln_t_kernel(const float* __restrict__ xf,
                                                   const float* __restrict__ g,
                                                   const float* __restrict__ bt,
                                                   unsigned short* __restrict__ xt) {
    int w = threadIdx.x >> 6, l = threadIdx.x & 63;
    int row = blockIdx.x * 4 + w;
    const float* src = xf + (size_t)row * TXT;
    float4 a0 = *(const float4*)&src[l * 12];
    float4 a1 = *(const float4*)&src[l * 12 + 4];
    float4 a2 = *(const float4*)&src[l * 12 + 8];
    float vals[12] = {a0.x, a0.y, a0.z, a0.w, a1.x, a1.y, a1.z, a1.w,
                      a2.x, a2.y, a2.z, a2.w};
    float s = 0.f, ss = 0.f;
#pragma unroll
    for (int j = 0; j < 12; ++j) { s += vals[j]; ss += vals[j] * vals[j]; }
#pragma unroll
    for (int m = 1; m <= 32; m <<= 1) { s += __shfl_xor(s, m); ss += __shfl_xor(ss, m); }
    float mean = s * (1.f / TXT), var = ss * (1.f / TXT) - mean * mean;
    float rs = rsqrtf(var + 1e-5f);
    unsigned short o[12];
#pragma unroll
    for (int j = 0; j < 12; ++j) {
        int c = l * 12 + j;
        o[j] = f2bf((vals[j] - mean) * rs * g[c] + bt[c]);
    }
    unsigned short* dp = xt + (size_t)row * TXT + l * 12;
    *(u16x4*)&dp[0] = *(u16x4*)&o[0];
    *(u16x4*)&dp[4] = *(u16x4*)&o[4];
    *(u16x4*)&dp[8] = *(u16x4*)&o[8];
}

// ---------------------------------------------------------------------------
// K0: A1 = LN(x) in bf16.  one wave per row.
// ---------------------------------------------------------------------------
__global__ void __launch_bounds__(256) ln_x_kernel(const float* __restrict__ x,
                                                   const float* __restrict__ g,
                                                   const float* __restrict__ bt,
                                                   unsigned short* __restrict__ A1) {
    int w = threadIdx.x >> 6, l = threadIdx.x & 63;
    int row = blockIdx.x * 4 + w;
    const float* src = x + (size_t)row * Dc;
    float4 a0 = *(const float4*)&src[l * 8];
    float4 a1 = *(const float4*)&src[l * 8 + 4];
    float vals[8] = {a0.x, a0.y, a0.z, a0.w, a1.x, a1.y, a1.z, a1.w};
    float s = 0.f, ss = 0.f;
#pragma unroll
    for (int j = 0; j < 8; ++j) { s += vals[j]; ss += vals[j] * vals[j]; }
#pragma unroll
    for (int m = 1; m <= 32; m <<= 1) { s += __shfl_xor(s, m); ss += __shfl_xor(ss, m); }
    float mean = s * (1.f / Dc), var = ss * (1.f / Dc) - mean * mean;
    float rs = rsqrtf(var + 1e-5f);
    u16x8 o;
#pragma unroll
    for (int j = 0; j < 8; ++j) {
        int c = l * 8 + j;
        o[j] = f2bf((vals[j] - mean) * rs * g[c] + bt[c]);
    }
    *(u16x8*)&A1[(size_t)row * Dc + l * 8] = o;
}

// ---------------------------------------------------------------------------
// kvgemm: [2048x768] @ [768x1024] -> k (softmaxed, bf16) | v (bf16)
// 128x128 tile, BK=64, 4 waves (2x2)
// ---------------------------------------------------------------------------
__global__ void __launch_bounds__(256) kvgemm_kernel(
    const unsigned short* __restrict__ xt, const unsigned short* __restrict__ Wkvt,
    const float* __restrict__ bk, const float* __restrict__ bv,
    unsigned short* __restrict__ kbuf, unsigned short* __restrict__ vbuf) {
    __shared__ short lds_s[16384];
    short* Alds = lds_s;
    short* Blds = lds_s + 8192;

    const int tid = threadIdx.x, l = tid & 63, w = tid >> 6;
    const int lr = l & 15, lg = l >> 4;
    int mt = blockIdx.x >> 3, nt = blockIdx.x & 7;
    int row0 = mt * 128, col0 = nt * 128;
    int wrow = (w >> 1) * 64, wcol = (w & 1) * 64;

    f32x4 acc[4][4] = {};
    const int cbase = w * 64 + l;

    for (int ks = 0; ks < 12; ++ks) {
#pragma unroll
        for (int i = 0; i < 4; ++i) {
            int c = i * 256 + cbase;
            int r = c >> 3, kc = c & 7;
            int koff = ks * 64 + ((kc ^ (r & 7)) << 3);
            gload16(xt + (size_t)(row0 + r) * TXT + koff, &Alds[((i * 4 + w) * 64) * 8]);
            gload16(Wkvt + (size_t)(col0 + r) * TXT + koff, &Blds[((i * 4 + w) * 64) * 8]);
        }
        __syncthreads();
#pragma unroll
        for (int kk = 0; kk < 2; ++kk) {
            int kcw = kk * 4 + lg;
            bf16x8v af[4], bfr[4];
#pragma unroll
            for (int i = 0; i < 4; ++i) {
                int r = wrow + i * 16 + lr;
                af[i] = *(bf16x8v*)&Alds[(r * 8 + (kcw ^ (r & 7))) * 8];
            }
#pragma unroll
            for (int j = 0; j < 4; ++j) {
                int n = wcol + j * 16 + lr;
                bfr[j] = *(bf16x8v*)&Blds[(n * 8 + (kcw ^ (n & 7))) * 8];
            }
#pragma unroll
            for (int i = 0; i < 4; ++i)
#pragma unroll
                for (int j = 0; j < 4; ++j)
                    acc[i][j] = MFMA16(af[i], bfr[j], acc[i][j]);
        }
        __syncthreads();
    }

    const bool kHalf = (col0 + wcol) < 512;
    int cj[4];
    float bias[4];
#pragma unroll
    for (int j = 0; j < 4; ++j) {
        cj[j] = col0 + wcol + j * 16 + lr;
        bias[j] = kHalf ? bk[cj[j]] : bv[cj[j] - 512];
    }
#pragma unroll
    for (int i = 0; i < 4; ++i)
#pragma unroll
        for (int reg = 0; reg < 4; ++reg) {
            float v0 = acc[i][0][reg] + bias[0], v1 = acc[i][1][reg] + bias[1];
            float v2 = acc[i][2][reg] + bias[2], v3 = acc[i][3][reg] + bias[3];
            if (kHalf) {
                float m = fmaxf(fmaxf(v0, v1), fmaxf(v2, v3));
                m = fmaxf(m, __shfl_xor(m, 1)); m = fmaxf(m, __shfl_xor(m, 2));
                m = fmaxf(m, __shfl_xor(m, 4)); m = fmaxf(m, __shfl_xor(m, 8));
                float e0 = __expf(v0 - m), e1 = __expf(v1 - m);
                float e2 = __expf(v2 - m), e3 = __expf(v3 - m);
                float ssum = e0 + e1 + e2 + e3;
                ssum += __shfl_xor(ssum, 1); ssum += __shfl_xor(ssum, 2);
                ssum += __shfl_xor(ssum, 4); ssum += __shfl_xor(ssum, 8);
                float inv = 1.f / ssum;
                v0 = e0 * inv; v1 = e1 * inv; v2 = e2 * inv; v3 = e3 * inv;
            }
            int r = row0 + wrow + i * 16 + 4 * lg + reg;
            float vv[4] = {v0, v1, v2, v3};
#pragma unroll
            for (int j = 0; j < 4; ++j) {
                if (kHalf) kbuf[(size_t)r * Dc + cj[j]] = f2bf(vv[j]);
                else       vbuf[(size_t)r * Dc + cj[j] - 512] = f2bf(vv[j]);
            }
        }
}

// ---------------------------------------------------------------------------
// attn_kernel: attn_t[b,h][l][d] = sum_n k[b,n,h,d]*v[b,n,h,l]  (bf16 in/out)
// ---------------------------------------------------------------------------
__global__ void attn_kernel(const unsigned short* __restrict__ kbuf,
                            const unsigned short* __restrict__ vbuf,
                            unsigned short* __restrict__ attn_t) {
    __shared__ float ks[16][DHc], vs[16][DHc];
    const int tid = threadIdx.x;
    const int b = blockIdx.x >> 3, h = blockIdx.x & 7;
    const int d = tid >> 2, lb = (tid & 3) * 16;
    float acc[16] = {0.f};
    for (int nt = 0; nt < 16; ++nt) {
        __syncthreads();
#pragma unroll
        for (int j = 0; j < 4; ++j) {
            int idx = tid + 256 * j;
            int nn = idx >> 6, cc = idx & 63;
            size_t o = (size_t)(b * NTOK + nt * 16 + nn) * Dc + h * DHc + cc;
            ks[nn][cc] = bf2f(kbuf[o]);
            vs[nn][cc] = bf2f(vbuf[o]);
        }
        __syncthreads();
#pragma unroll
        for (int nn = 0; nn < 16; ++nn) {
            float kd = ks[nn][d];
#pragma unroll
            for (int i = 0; i < 16; ++i) acc[i] += kd * vs[nn][lb + i];
        }
    }
    size_t base = (size_t)(b * 8 + h) * DHc * DHc;
#pragma unroll
    for (int i = 0; i < 16; ++i)
        attn_t[base + (size_t)(lb + i) * DHc + d] = f2bf(acc[i]);
}

// ---------------------------------------------------------------------------
// emb_kernel: eo[b,:] = silu(emb[b]) @ emb_W + emb_b   (k-split x4, 128 blocks)
// ---------------------------------------------------------------------------
__global__ void __launch_bounds__(256) emb_kernel(const float* __restrict__ emb,
                                                  const float* __restrict__ emb_W,
                                                  const float* __restrict__ emb_b,
                                                  float* __restrict__ eo) {
    __shared__ float s[TEc];
    __shared__ float red[4][64];
    const int tid = threadIdx.x;
    const int b = blockIdx.x >> 4, chunk = blockIdx.x & 15;
#pragma unroll
    for (int j = 0; j < 8; ++j) {
        int idx = tid + 256 * j;
        float e = emb[b * TEc + idx];
        s[idx] = e / (1.f + __expf(-e));
    }
    __syncthreads();
    int c = tid & 63, q = tid >> 6;
    int col = chunk * 64 + c;
    float acc = 0.f;
    for (int kk = q * 512; kk < q * 512 + 512; ++kk)
        acc += s[kk] * emb_W[(size_t)kk * (2 * Dc) + col];
    red[q][c] = acc;
    __syncthreads();
    if (q == 0)
        eo[b * (2 * Dc) + col] = red[0][c] + red[1][c] + red[2][c] + red[3][c] + emb_b[col];
}

// ---------------------------------------------------------------------------
// KA: GEMM1 (A1 @ Wq_t) + bq + per-head softmax + (q @ attn) -> out1 bf16
// ---------------------------------------------------------------------------
__global__ void __launch_bounds__(256) gemm1_kernel(
    const unsigned short* __restrict__ A1, const unsigned short* __restrict__ Wt,
    const float* __restrict__ bq, const unsigned short* __restrict__ attn_t,
    unsigned short* __restrict__ out1) {
    __shared__ short lds_s[16384];
    short* Alds = lds_s;
    short* Blds = lds_s + 8192;

    const int tid = threadIdx.x, l = tid & 63, w = tid >> 6;
    const int lr = l & 15, lg = l >> 4;
    int raw = blockIdx.x;
    int swz = (raw & 7) * 256 + (raw >> 3);
    int mt = swz >> 2, nt = swz & 3;
    int row0 = mt * 128, col0 = nt * 128;
    int b = row0 >> 13;
    int wrow = (w >> 1) * 64, wcol = (w & 1) * 64;

    f32x4 acc[4][4] = {};
    const int cbase = w * 64 + l;

    for (int ks = 0; ks < 8; ++ks) {
#pragma unroll
        for (int i = 0; i < 4; ++i) {
            int c = i * 256 + cbase;
            int r = c >> 3, kc = c & 7;
            int koff = ks * 64 + ((kc ^ (r & 7)) << 3);
            gload16(A1 + (size_t)(row0 + r) * Dc + koff, &Alds[((i * 4 + w) * 64) * 8]);
            gload16(Wt + (size_t)(col0 + r) * Dc + koff, &Blds[((i * 4 + w) * 64) * 8]);
        }
        __syncthreads();
#pragma unroll
        for (int kk = 0; kk < 2; ++kk) {
            int kcw = kk * 4 + lg;
            bf16x8v af[4], bfr[4];
#pragma unroll
            for (int i = 0; i < 4; ++i) {
                int r = wrow + i * 16 + lr;
                af[i] = *(bf16x8v*)&Alds[(r * 8 + (kcw ^ (r & 7))) * 8];
            }
#pragma unroll
            for (int j = 0; j < 4; ++j) {
                int n = wcol + j * 16 + lr;
                bfr[j] = *(bf16x8v*)&Blds[(n * 8 + (kcw ^ (n & 7))) * 8];
            }
#pragma unroll
            for (int i = 0; i < 4; ++i)
#pragma unroll
                for (int j = 0; j < 4; ++j)
                    acc[i][j] = MFMA16(af[i], bfr[j], acc[i][j]);
        }
        __syncthreads();
    }

    float bqv[4];
#pragma unroll
    for (int j = 0; j < 4; ++j) bqv[j] = bq[col0 + wcol + j * 16 + lr];
#pragma unroll
    for (int i = 0; i < 4; ++i)
#pragma unroll
        for (int reg = 0; reg < 4; ++reg) {
            float v0 = acc[i][0][reg] + bqv[0], v1 = acc[i][1][reg] + bqv[1];
            float v2 = acc[i][2][reg] + bqv[2], v3 = acc[i][3][reg] + bqv[3];
            float m = fmaxf(fmaxf(v0, v1), fmaxf(v2, v3));
            m = fmaxf(m, __shfl_xor(m, 1)); m = fmaxf(m, __shfl_xor(m, 2));
            m = fmaxf(m, __shfl_xor(m, 4)); m = fmaxf(m, __shfl_xor(m, 8));
            float e0 = __expf(v0 - m), e1 = __expf(v1 - m);
            float e2 = __expf(v2 - m), e3 = __expf(v3 - m);
            float ssum = e0 + e1 + e2 + e3;
            ssum += __shfl_xor(ssum, 1); ssum += __shfl_xor(ssum, 2);
            ssum += __shfl_xor(ssum, 4); ssum += __shfl_xor(ssum, 8);
            float inv = 1.f / ssum;
            acc[i][0][reg] = e0 * inv; acc[i][1][reg] = e1 * inv;
            acc[i][2][reg] = e2 * inv; acc[i][3][reg] = e3 * inv;
        }

    short* qlds = lds_s;
#pragma unroll
    for (int i = 0; i < 4; ++i)
#pragma unroll
        for (int j = 0; j < 4; ++j)
#pragma unroll
            for (int reg = 0; reg < 4; ++reg) {
                int r = wrow + i * 16 + 4 * lg + reg;
                int c = wcol + j * 16 + lr;
                qlds[(r * 16 + ((c >> 3) ^ (r & 7))) * 8 + (c & 7)] = (short)f2bf(acc[i][j][reg]);
            }
    __syncthreads();

    int hw = nt * 2 + (wcol >> 6);
    const unsigned short* at = attn_t + (size_t)(b * 8 + hw) * DHc * DHc;
    bf16x8v bf2[4][2];
#pragma unroll
    for (int j = 0; j < 4; ++j)
#pragma unroll
        for (int kk = 0; kk < 2; ++kk)
            bf2[j][kk] = *(const bf16x8v*)&at[(j * 16 + lr) * DHc + kk * 32 + lg * 8];

    f32x4 acc2[4][4] = {};
#pragma unroll
    for (int kk = 0; kk < 2; ++kk) {
        int kcw = (wcol >> 3) + kk * 4 + lg;
#pragma unroll
        for (int i = 0; i < 4; ++i) {
            int r = wrow + i * 16 + lr;
            bf16x8v a = *(bf16x8v*)&qlds[(r * 16 + (kcw ^ (r & 7))) * 8];
#pragma unroll
            for (int j = 0; j < 4; ++j)
                acc2[i][j] = MFMA16(a, bf2[j][kk], acc2[i][j]);
        }
    }

#pragma unroll
    for (int i = 0; i < 4; ++i)
#pragma unroll
        for (int j = 0; j < 4; ++j)
#pragma unroll
            for (int reg = 0; reg < 4; ++reg) {
                int r = row0 + wrow + i * 16 + 4 * lg + reg;
                int c = col0 + wcol + j * 16 + lr;
                out1[(size_t)r * Dc + c] = f2bf(acc2[i][j][reg]);
            }
}

// ---------------------------------------------------------------------------
// Kmid: A2 = bf16( silu( LN(out1)*(1+scale)+shift ) )
// ---------------------------------------------------------------------------
__global__ void __launch_bounds__(256) mid_kernel(const unsigned short* __restrict__ out1,
                                                  const float* __restrict__ eo,
                                                  const float* __restrict__ g,
                                                  const float* __restrict__ bt,
                                                  unsigned short* __restrict__ A2) {
    int w = threadIdx.x >> 6, l = threadIdx.x & 63;
    int row = blockIdx.x * 4 + w;
    int b = row >> 13;
    u16x8 iv = *(const u16x8*)&out1[(size_t)row * Dc + l * 8];
    float vals[8];
    float s = 0.f, ss = 0.f;
#pragma unroll
    for (int j = 0; j < 8; ++j) {
        vals[j] = bf2f(iv[j]);
        s += vals[j]; ss += vals[j] * vals[j];
    }
#pragma unroll
    for (int m = 1; m <= 32; m <<= 1) { s += __shfl_xor(s, m); ss += __shfl_xor(ss, m); }
    float mean = s * (1.f / Dc), var = ss * (1.f / Dc) - mean * mean;
    float rs = rsqrtf(var + 1e-5f);
    const float* scl = eo + (size_t)b * (2 * Dc);
    const float* shf = scl + Dc;
    u16x8 o;
#pragma unroll
    for (int j = 0; j < 8; ++j) {
        int c = l * 8 + j;
        float t = (vals[j] - mean) * rs * g[c] + bt[c];
        t = t * (1.f + scl[c]) + shf[c];
        t = t / (1.f + __expf(-t));
        o[j] = f2bf(t);
    }
    *(u16x8*)&A2[(size_t)row * Dc + l * 8] = o;
}

// ---------------------------------------------------------------------------
// KB: out = x + (A2 @ oW_t) + out_b    (fp32 output)
// ---------------------------------------------------------------------------
__global__ void __launch_bounds__(256) gemm2_kernel(
    const unsigned short* __restrict__ A2, const unsigned short* __restrict__ Wt,
    const float* __restrict__ ob, const float* __restrict__ x,
    float* __restrict__ out) {
    __shared__ short lds_s[16384];
    short* Alds = lds_s;
    short* Blds = lds_s + 8192;

    const int tid = threadIdx.x, l = tid & 63, w = tid >> 6;
    const int lr = l & 15, lg = l >> 4;
    int raw = blockIdx.x;
    int swz = (raw & 7) * 256 + (raw >> 3);
    int mt = swz >> 2, nt = swz & 3;
    int row0 = mt * 128, col0 = nt * 128;
    int wrow = (w >> 1) * 64, wcol = (w & 1) * 64;

    f32x4 acc[4][4] = {};
    const int cbase = w * 64 + l;

    for (int ks = 0; ks < 8; ++ks) {
#pragma unroll
        for (int i = 0; i < 4; ++i) {
            int c = i * 256 + cbase;
            int r = c >> 3, kc = c & 7;
            int koff = ks * 64 + ((kc ^ (r & 7)) << 3);
            gload16(A2 + (size_t)(row0 + r) * Dc + koff, &Alds[((i * 4 + w) * 64) * 8]);
            gload16(Wt + (size_t)(col0 + r) * Dc + koff, &Blds[((i * 4 + w) * 64) * 8]);
        }
        __syncthreads();
#pragma unroll
        for (int kk = 0; kk < 2; ++kk) {
            int kcw = kk * 4 + lg;
            bf16x8v af[4], bfr[4];
#pragma unroll
            for (int i = 0; i < 4; ++i) {
                int r = wrow + i * 16 + lr;
                af[i] = *(bf16x8v*)&Alds[(r * 8 + (kcw ^ (r & 7))) * 8];
            }
#pragma unroll
            for (int j = 0; j < 4; ++j) {
                int n = wcol + j * 16 + lr;
                bfr[j] = *(bf16x8v*)&Blds[(n * 8 + (kcw ^ (n & 7))) * 8];
            }
#pragma unroll
            for (int i = 0; i < 4; ++i)
#pragma unroll
                for (int j = 0; j < 4; ++j)
                    acc[i][j] = MFMA16(af[i], bfr[j], acc[i][j]);
        }
        __syncthreads();
    }

    float obv[4];
#pragma unroll
    for (int j = 0; j < 4; ++j) obv[j] = ob[col0 + wcol + j * 16 + lr];
#pragma unroll
    for (int i = 0; i < 4; ++i)
#pragma unroll
        for (int j = 0; j < 4; ++j)
#pragma unroll
            for (int reg = 0; reg < 4; ++reg) {
                int r = row0 + wrow + i * 16 + 4 * lg + reg;
                int c = col0 + wcol + j * 16 + lr;
                size_t o = (size_t)r * Dc + c;
                out[o] = acc[i][j][reg] + obv[j] + x[o];
            }
}

// ---------------------------------------------------------------------------
extern "C" void kernel_launch(void* const* d_in, const int* in_sizes, int n_in,
                              void* d_out, int out_size, void* d_ws, size_t ws_size,
                              hipStream_t stream) {
    const float* x      = (const float*)d_in[0];
    const float* xf     = (const float*)d_in[1];
    const float* emb    = (const float*)d_in[2];
    const float* ln_x_g = (const float*)d_in[3];
    const float* ln_x_b = (const float*)d_in[4];
    const float* ln_t_g = (const float*)d_in[5];
    const float* ln_t_b = (const float*)d_in[6];
    const float* Wq     = (const float*)d_in[7];
    const float* bq     = (const float*)d_in[8];
    const float* Wk     = (const float*)d_in[9];
    const float* bk     = (const float*)d_in[10];
    const float* Wv     = (const float*)d_in[11];
    const float* bv     = (const float*)d_in[12];
    const float* emb_W  = (const float*)d_in[13];
    const float* emb_b  = (const float*)d_in[14];
    const float* ln_o_g = (const float*)d_in[15];
    const float* ln_o_b = (const float*)d_in[16];
    const float* out_W  = (const float*)d_in[17];
    const float* out_b  = (const float*)d_in[18];
    float* out = (float*)d_out;

    // ws layout (bf16 unless noted)
    unsigned short* xt   = (unsigned short*)d_ws;                 // 2048*768
    unsigned short* kbuf = xt + (size_t)2048 * TXT;               // 2048*512
    unsigned short* vbuf = kbuf + (size_t)2048 * 512;             // 2048*512
    unsigned short* Wkvt = vbuf + (size_t)2048 * 512;             // 1024*768
    unsigned short* Wqt  = Wkvt + (size_t)1024 * TXT;             // 512*512
    unsigned short* oWt  = Wqt + (size_t)512 * 512;               // 512*512
    unsigned short* attn_t = oWt + (size_t)512 * 512;             // 64*64*64
    float* eo = (float*)(attn_t + (size_t)64 * 64 * 64);          // 8*1024 f32
    unsigned short* A1 = (unsigned short*)(eo + 8 * 1024);        // 65536*512
    unsigned short* A2 = A1;                                      // overlay
    unsigned short* out1 = (unsigned short*)d_out;                // first half of d_out

    // weight transposes (tiled, coalesced)
    hipLaunchKernelGGL(transpose_kernel, dim3(8, 8), dim3(256), 0, stream, Wq, Wqt, Dc, Dc);
    hipLaunchKernelGGL(transpose_kernel, dim3(8, 8), dim3(256), 0, stream, out_W, oWt, Dc, Dc);
    hipLaunchKernelGGL(transpose_kernel, dim3(12, 8), dim3(256), 0, stream, Wk, Wkvt, Dc, TXT);
    hipLaunchKernelGGL(transpose_kernel, dim3(12, 8), dim3(256), 0, stream,
                       Wv, Wkvt + (size_t)512 * TXT, Dc, TXT);

    hipLaunchKernelGGL(ln_t_kernel, dim3(NTOK * Bc / 4), dim3(256), 0, stream,
                       xf, ln_t_g, ln_t_b, xt);
    hipLaunchKernelGGL(ln_x_kernel, dim3(MROWS / 4), dim3(256), 0, stream, x, ln_x_g, ln_x_b, A1);
    hipLaunchKernelGGL(kvgemm_kernel, dim3(16 * 8), dim3(256), 0, stream,
                       xt, Wkvt, bk, bv, kbuf, vbuf);
    hipLaunchKernelGGL(attn_kernel, dim3(Bc * Hc), dim3(256), 0, stream, kbuf, vbuf, attn_t);
    hipLaunchKernelGGL(emb_kernel, dim3(Bc * 16), dim3(256), 0, stream, emb, emb_W, emb_b, eo);
    hipLaunchKernelGGL(gemm1_kernel, dim3(MROWS / 128 * 4), dim3(256), 0, stream,
                       A1, Wqt, bq, attn_t, out1);
    hipLaunchKernelGGL(mid_kernel, dim3(MROWS / 4), dim3(256), 0, stream,
                       out1, eo, ln_o_g, ln_o_b, A2);
    hipLaunchKernelGGL(gemm2_kernel, dim3(MROWS / 128 * 4), dim3(256), 0, stream,
                       A2, oWt, out_b, x, out);
}